// Round 2
// baseline (321.827 us; speedup 1.0000x reference)
//
#include <hip/hip_runtime.h>
#include <hip/hip_cooperative_groups.h>

namespace cg = cooperative_groups;

// DTFormer: B=64, L=1024, S=8, D=128
// Single cooperative kernel:
//   phase 1: zero global hist (4 MB in ws) + build Phi table[8][16][16][128]
//            (one row per wave, shuffle-reduce, zero LDS)
//   sync
//   phase 2: per-batch histogram over packed (id,snap) keys, global atomics
//            (src count in lo16, dst count in hi16)
//   sync
//   phase 3: gather Phi[sn][c0][c1] per (side,b,l), 67 MB coalesced write
// Exact slow path for counts >= 16 (Poisson(0.064) input: never taken).

#define LSEQ    1024
#define NBATCH  64
#define DDIM    128
#define NKEYS   16384
#define CMAX    16
#define NTHREADS 256
#define MAXBLOCKS 1024
#define NUNITS  (2 * NBATCH * LSEQ)          // 131072
#define NQUADS  (NUNITS * (DDIM / 4))        // 4194304 float4s of output

__device__ __forceinline__ void slow_path(
    unsigned int c0, unsigned int c1, unsigned int snz, int q,
    const float* __restrict__ agg_w1, const float* __restrict__ agg_b1,
    const float* __restrict__ agg_w2, const float* __restrict__ agg_b2,
    const float* __restrict__ enc_w1, const float* __restrict__ enc_b1,
    const float* __restrict__ enc_w2, const float* __restrict__ enc_b2,
    float4* v)
{
    float s0 = 0.0f, s1 = 0.0f;
    for (int dd = 0; dd < DDIM; ++dd) {
        const float w1d = agg_w1[snz * DDIM + dd];
        const float b1d = agg_b1[dd];
        const float h = fmaxf((float)c0 * w1d + b1d, 0.0f)
                      + fmaxf((float)c1 * w1d + b1d, 0.0f);
        s0 += h * agg_w2[dd * 2 + 0];
        s1 += h * agg_w2[dd * 2 + 1];
    }
    const float y0 = agg_b2[0] + 0.5f * s0;
    const float y1 = agg_b2[1] + 0.5f * s1;
    float o0 = 2.0f * enc_b2[q * 4 + 0];
    float o1 = 2.0f * enc_b2[q * 4 + 1];
    float o2 = 2.0f * enc_b2[q * 4 + 2];
    float o3 = 2.0f * enc_b2[q * 4 + 3];
    for (int k = 0; k < DDIM; ++k) {
        const float w1e = enc_w1[k], b1e = enc_b1[k];
        const float gk = fmaxf(y0 * w1e + b1e, 0.0f)
                       + fmaxf(y1 * w1e + b1e, 0.0f);
        o0 += gk * enc_w2[k * DDIM + q * 4 + 0];
        o1 += gk * enc_w2[k * DDIM + q * 4 + 1];
        o2 += gk * enc_w2[k * DDIM + q * 4 + 2];
        o3 += gk * enc_w2[k * DDIM + q * 4 + 3];
    }
    *v = make_float4(o0, o1, o2, o3);
}

__device__ __forceinline__ void phase_zero_table(
    int tid, int stride,
    const float* __restrict__ agg_w1, const float* __restrict__ agg_b1,
    const float* __restrict__ agg_w2, const float* __restrict__ agg_b2,
    const float* __restrict__ enc_w1, const float* __restrict__ enc_b1,
    const float* __restrict__ enc_w2, const float* __restrict__ enc_b2,
    unsigned int* __restrict__ hist, float* __restrict__ table)
{
    // zero the 4 MB histogram
    uint4* h4 = (uint4*)hist;
    const uint4 z = make_uint4(0u, 0u, 0u, 0u);
    for (int i = tid; i < (NBATCH * NKEYS) / 4; i += stride) h4[i] = z;

    // Phi table: one row (sn,c0,c1) per wave, grid-stride over 2048 rows
    const int lane = threadIdx.x & 63;
    const int nwaves = stride >> 6;
    for (int r = tid >> 6; r < 8 * CMAX * CMAX; r += nwaves) {
        const int sn = r >> 8;
        const int c0 = (r >> 4) & 15;
        const int c1 = r & 15;
        float p0 = 0.0f, p1 = 0.0f;
        #pragma unroll
        for (int half = 0; half < 2; ++half) {
            const int d = lane + half * 64;
            const float w1d = agg_w1[sn * DDIM + d];
            const float b1d = agg_b1[d];
            const float h = fmaxf((float)c0 * w1d + b1d, 0.0f)
                          + fmaxf((float)c1 * w1d + b1d, 0.0f);
            p0 += h * agg_w2[d * 2 + 0];
            p1 += h * agg_w2[d * 2 + 1];
        }
        #pragma unroll
        for (int m = 32; m; m >>= 1) {
            p0 += __shfl_xor(p0, m, 64);
            p1 += __shfl_xor(p1, m, 64);
        }
        const float y0 = agg_b2[0] + 0.5f * p0;
        const float y1 = agg_b2[1] + 0.5f * p1;
        float a0 = 2.0f * enc_b2[lane];
        float a1 = 2.0f * enc_b2[lane + 64];
        #pragma unroll 4
        for (int k = 0; k < DDIM; ++k) {
            const float w1e = enc_w1[k], b1e = enc_b1[k];
            const float gk = fmaxf(y0 * w1e + b1e, 0.0f)
                           + fmaxf(y1 * w1e + b1e, 0.0f);
            a0 += gk * enc_w2[k * DDIM + lane];
            a1 += gk * enc_w2[k * DDIM + lane + 64];
        }
        table[r * DDIM + lane]      = a0;
        table[r * DDIM + lane + 64] = a1;
    }
}

__device__ __forceinline__ void phase_hist(
    int tid, int stride,
    const int* __restrict__ src_ids, const int* __restrict__ dst_ids,
    const int* __restrict__ src_sn,  const int* __restrict__ dst_sn,
    unsigned int* __restrict__ hist)
{
    for (int i = tid; i < NUNITS; i += stride) {
        const int side = i >> 16;
        const int idx  = i & 65535;
        const int id = side ? dst_ids[idx] : src_ids[idx];
        const int sn = side ? dst_sn[idx]  : src_sn[idx];
        unsigned int key = (unsigned int)(id * 8 + ((sn - 1) & 7));
        if (key >= NKEYS) key = NKEYS - 1;   // never hit: id < 2000
        atomicAdd(&hist[(idx >> 10) * NKEYS + key], side ? 65536u : 1u);
    }
}

__device__ __forceinline__ void phase_gather(
    int tid, int stride,
    const int* __restrict__ src_ids, const int* __restrict__ dst_ids,
    const int* __restrict__ src_sn,  const int* __restrict__ dst_sn,
    const unsigned int* __restrict__ hist, const float* __restrict__ table,
    const float* __restrict__ agg_w1, const float* __restrict__ agg_b1,
    const float* __restrict__ agg_w2, const float* __restrict__ agg_b2,
    const float* __restrict__ enc_w1, const float* __restrict__ enc_b1,
    const float* __restrict__ enc_w2, const float* __restrict__ enc_b2,
    float* __restrict__ out)
{
    float4* out4 = (float4*)out;
    #pragma unroll 2
    for (int gt = tid; gt < NQUADS; gt += stride) {
        const int unit = gt >> 5;
        const int q    = gt & 31;
        const int side = unit >> 16;
        const int idx  = unit & 65535;
        const int id = side ? dst_ids[idx] : src_ids[idx];
        const int sn = side ? dst_sn[idx]  : src_sn[idx];
        const unsigned int snz = (unsigned int)((sn - 1) & 7);
        unsigned int key = (unsigned int)(id * 8 + snz);
        if (key >= NKEYS) key = NKEYS - 1;
        const unsigned int h = hist[(idx >> 10) * NKEYS + key];
        const unsigned int lo = h & 0xffffu, hi = h >> 16;
        const unsigned int valid = (id != 0) ? 1u : 0u;
        const unsigned int c0 = (side ? hi : lo) * valid;
        const unsigned int c1 = (side ? lo : hi) * valid;

        float4 v;
        if (c0 < CMAX && c1 < CMAX) {
            v = ((const float4*)(table
                + ((snz * 16u + c0) * 16u + c1) * DDIM))[q];
        } else {
            slow_path(c0, c1, snz, q, agg_w1, agg_b1, agg_w2, agg_b2,
                      enc_w1, enc_b1, enc_w2, enc_b2, &v);
        }
        out4[gt] = v;
    }
}

__global__ __launch_bounds__(NTHREADS, 4) void fused_kernel(
    const int* __restrict__ src_ids, const int* __restrict__ dst_ids,
    const int* __restrict__ src_sn,  const int* __restrict__ dst_sn,
    const float* __restrict__ agg_w1, const float* __restrict__ agg_b1,
    const float* __restrict__ agg_w2, const float* __restrict__ agg_b2,
    const float* __restrict__ enc_w1, const float* __restrict__ enc_b1,
    const float* __restrict__ enc_w2, const float* __restrict__ enc_b2,
    unsigned int* __restrict__ hist, float* __restrict__ table,
    float* __restrict__ out)
{
    const int tid    = blockIdx.x * NTHREADS + threadIdx.x;
    const int stride = gridDim.x * NTHREADS;

    phase_zero_table(tid, stride, agg_w1, agg_b1, agg_w2, agg_b2,
                     enc_w1, enc_b1, enc_w2, enc_b2, hist, table);
    cg::this_grid().sync();
    phase_hist(tid, stride, src_ids, dst_ids, src_sn, dst_sn, hist);
    cg::this_grid().sync();
    phase_gather(tid, stride, src_ids, dst_ids, src_sn, dst_sn, hist, table,
                 agg_w1, agg_b1, agg_w2, agg_b2,
                 enc_w1, enc_b1, enc_w2, enc_b2, out);
}

// -------- non-cooperative fallback (3 launches, same device code) ----------
__global__ __launch_bounds__(NTHREADS, 4) void k_zero_table(
    const float* __restrict__ agg_w1, const float* __restrict__ agg_b1,
    const float* __restrict__ agg_w2, const float* __restrict__ agg_b2,
    const float* __restrict__ enc_w1, const float* __restrict__ enc_b1,
    const float* __restrict__ enc_w2, const float* __restrict__ enc_b2,
    unsigned int* __restrict__ hist, float* __restrict__ table)
{
    phase_zero_table(blockIdx.x * NTHREADS + threadIdx.x, gridDim.x * NTHREADS,
                     agg_w1, agg_b1, agg_w2, agg_b2,
                     enc_w1, enc_b1, enc_w2, enc_b2, hist, table);
}
__global__ __launch_bounds__(NTHREADS, 4) void k_hist(
    const int* __restrict__ src_ids, const int* __restrict__ dst_ids,
    const int* __restrict__ src_sn,  const int* __restrict__ dst_sn,
    unsigned int* __restrict__ hist)
{
    phase_hist(blockIdx.x * NTHREADS + threadIdx.x, gridDim.x * NTHREADS,
               src_ids, dst_ids, src_sn, dst_sn, hist);
}
__global__ __launch_bounds__(NTHREADS, 4) void k_gather(
    const int* __restrict__ src_ids, const int* __restrict__ dst_ids,
    const int* __restrict__ src_sn,  const int* __restrict__ dst_sn,
    const unsigned int* __restrict__ hist, const float* __restrict__ table,
    const float* __restrict__ agg_w1, const float* __restrict__ agg_b1,
    const float* __restrict__ agg_w2, const float* __restrict__ agg_b2,
    const float* __restrict__ enc_w1, const float* __restrict__ enc_b1,
    const float* __restrict__ enc_w2, const float* __restrict__ enc_b2,
    float* __restrict__ out)
{
    phase_gather(blockIdx.x * NTHREADS + threadIdx.x, gridDim.x * NTHREADS,
                 src_ids, dst_ids, src_sn, dst_sn, hist, table,
                 agg_w1, agg_b1, agg_w2, agg_b2,
                 enc_w1, enc_b1, enc_w2, enc_b2, out);
}

extern "C" void kernel_launch(void* const* d_in, const int* in_sizes, int n_in,
                              void* d_out, int out_size, void* d_ws, size_t ws_size,
                              hipStream_t stream)
{
    const int* src_ids = (const int*)d_in[0];
    const int* dst_ids = (const int*)d_in[1];
    const int* src_sn  = (const int*)d_in[2];
    const int* dst_sn  = (const int*)d_in[3];
    const float* agg_w1 = (const float*)d_in[5];
    const float* agg_b1 = (const float*)d_in[6];
    const float* agg_w2 = (const float*)d_in[7];
    const float* agg_b2 = (const float*)d_in[8];
    const float* enc_w1 = (const float*)d_in[9];
    const float* enc_b1 = (const float*)d_in[10];
    const float* enc_w2 = (const float*)d_in[11];
    const float* enc_b2 = (const float*)d_in[12];
    float* out = (float*)d_out;

    // ws: hist[64*16384] u32 (4 MB) | table[2048*128] f32 (1 MB)
    unsigned int* hist = (unsigned int*)d_ws;
    float* table = (float*)(hist + NBATCH * NKEYS);

    int maxb = 0;
    hipError_t qerr = hipOccupancyMaxActiveBlocksPerMultiprocessor(
        &maxb, fused_kernel, NTHREADS, 0);
    int grid = MAXBLOCKS;
    if (qerr == hipSuccess && maxb > 0) {
        const int cap = maxb * 256;          // 256 CUs
        if (cap < grid) grid = cap;
    } else {
        grid = 512;
    }

    void* kargs[] = {
        (void*)&src_ids, (void*)&dst_ids, (void*)&src_sn, (void*)&dst_sn,
        (void*)&agg_w1, (void*)&agg_b1, (void*)&agg_w2, (void*)&agg_b2,
        (void*)&enc_w1, (void*)&enc_b1, (void*)&enc_w2, (void*)&enc_b2,
        (void*)&hist, (void*)&table, (void*)&out
    };
    hipError_t lerr = hipLaunchCooperativeKernel(
        (void*)fused_kernel, dim3(grid), dim3(NTHREADS), kargs, 0, stream);

    if (lerr != hipSuccess) {
        (void)hipGetLastError();   // clear error state
        k_zero_table<<<MAXBLOCKS, NTHREADS, 0, stream>>>(
            agg_w1, agg_b1, agg_w2, agg_b2,
            enc_w1, enc_b1, enc_w2, enc_b2, hist, table);
        k_hist<<<256, NTHREADS, 0, stream>>>(
            src_ids, dst_ids, src_sn, dst_sn, hist);
        k_gather<<<MAXBLOCKS * 4, NTHREADS, 0, stream>>>(
            src_ids, dst_ids, src_sn, dst_sn, hist, table,
            agg_w1, agg_b1, agg_w2, agg_b2,
            enc_w1, enc_b1, enc_w2, enc_b2, out);
    }
}

// Round 3
// 126.548 us; speedup vs baseline: 2.5431x; 2.5431x over previous
//
#include <hip/hip_runtime.h>

// DTFormer: B=64, L=1024, S=8, D=128
// Two-kernel pipeline (cooperative fusion regressed 2x in R2 -- reverted):
//  K1 (mixed, independent halves, no intra-kernel dependency):
//    blocks 0..63   : per-batch LDS histogram over packed (id,snap) keys ->
//                     per-unit table ROW INDEX (or slow-path descriptor)
//    blocks 64..191 : Phi table [8][16][16][128], one row per wave,
//                     shuffle-reduce, no LDS use
//  K2: gather: 4 float4 per thread, coalesced nontemporal 67MB write.
// Exact slow path for counts >= 16 (Poisson(0.064) input: never taken).

#define LSEQ    1024
#define NBATCH  64
#define DDIM    128
#define NKEYS   16384
#define CMAX    16
#define NUNITS  (2 * NBATCH * LSEQ)          // 131072
#define NQUADS  (NUNITS * (DDIM / 4))        // 4194304 float4s of output

// ------------------------------ K1 ----------------------------------------
__global__ __launch_bounds__(1024) void prep_kernel(
    const int* __restrict__ src_ids, const int* __restrict__ dst_ids,
    const int* __restrict__ src_sn,  const int* __restrict__ dst_sn,
    const float* __restrict__ agg_w1, const float* __restrict__ agg_b1,
    const float* __restrict__ agg_w2, const float* __restrict__ agg_b2,
    const float* __restrict__ enc_w1, const float* __restrict__ enc_b1,
    const float* __restrict__ enc_w2, const float* __restrict__ enc_b2,
    unsigned int* __restrict__ rowinfo, float* __restrict__ table)
{
    __shared__ unsigned int hist[NKEYS];   // src count lo16, dst count hi16

    if (blockIdx.x < NBATCH) {
        // ---- per-batch histogram + rowinfo ----
        const int b = blockIdx.x;
        const int t = threadIdx.x;

        uint4* h4 = (uint4*)hist;
        const uint4 z = make_uint4(0u, 0u, 0u, 0u);
        #pragma unroll
        for (int i = 0; i < NKEYS / 4 / 1024; ++i) h4[t + i * 1024] = z;
        __syncthreads();

        const int base = b * LSEQ;
        const int sid = src_ids[base + t];
        const int ssn = src_sn[base + t];
        const int did = dst_ids[base + t];
        const int dsn = dst_sn[base + t];

        const unsigned int ssnz = (unsigned int)((ssn - 1) & 7);
        const unsigned int dsnz = (unsigned int)((dsn - 1) & 7);
        unsigned int skey = (unsigned int)(sid * 8) + ssnz;
        unsigned int dkey = (unsigned int)(did * 8) + dsnz;
        if (skey >= NKEYS) skey = NKEYS - 1;   // never hit: id < 2000
        if (dkey >= NKEYS) dkey = NKEYS - 1;

        atomicAdd(&hist[skey], 1u);
        atomicAdd(&hist[dkey], 65536u);
        __syncthreads();

        const unsigned int hs = hist[skey];
        const unsigned int hd = hist[dkey];
        const unsigned int sv = (sid != 0) ? 1u : 0u;
        const unsigned int dv = (did != 0) ? 1u : 0u;
        const unsigned int sc0 = (hs & 0xffffu) * sv;   // src self
        const unsigned int sc1 = (hs >> 16) * sv;       // src cross
        const unsigned int dc0 = (hd >> 16) * dv;       // dst self
        const unsigned int dc1 = (hd & 0xffffu) * dv;   // dst cross

        // fast: row index (11 bits). slow: bit31 | c0 | c1<<11 | snz<<22
        unsigned int si, di;
        if (sc0 < CMAX && sc1 < CMAX)
            si = (ssnz << 8) | (sc0 << 4) | sc1;
        else
            si = 0x80000000u | sc0 | (sc1 << 11) | (ssnz << 22);
        if (dc0 < CMAX && dc1 < CMAX)
            di = (dsnz << 8) | (dc0 << 4) | dc1;
        else
            di = 0x80000000u | dc0 | (dc1 << 11) | (dsnz << 22);

        rowinfo[base + t]                   = si;
        rowinfo[NBATCH * LSEQ + base + t]   = di;
    } else {
        // ---- Phi table: one row per wave, shuffle-reduce ----
        const int wave = threadIdx.x >> 6;
        const int lane = threadIdx.x & 63;
        const int r = (blockIdx.x - NBATCH) * 16 + wave;   // [0, 2048)
        const int sn = r >> 8;
        const int c0 = (r >> 4) & 15;
        const int c1 = r & 15;

        float p0 = 0.0f, p1 = 0.0f;
        #pragma unroll
        for (int half = 0; half < 2; ++half) {
            const int d = lane + half * 64;
            const float w1d = agg_w1[sn * DDIM + d];
            const float b1d = agg_b1[d];
            const float h = fmaxf((float)c0 * w1d + b1d, 0.0f)
                          + fmaxf((float)c1 * w1d + b1d, 0.0f);
            p0 += h * agg_w2[d * 2 + 0];
            p1 += h * agg_w2[d * 2 + 1];
        }
        #pragma unroll
        for (int m = 32; m; m >>= 1) {
            p0 += __shfl_xor(p0, m, 64);
            p1 += __shfl_xor(p1, m, 64);
        }
        const float y0 = agg_b2[0] + 0.5f * p0;
        const float y1 = agg_b2[1] + 0.5f * p1;

        float a0 = 2.0f * enc_b2[lane];
        float a1 = 2.0f * enc_b2[lane + 64];
        #pragma unroll 4
        for (int k = 0; k < DDIM; ++k) {
            const float w1e = enc_w1[k], b1e = enc_b1[k];
            const float gk = fmaxf(y0 * w1e + b1e, 0.0f)
                           + fmaxf(y1 * w1e + b1e, 0.0f);
            a0 += gk * enc_w2[k * DDIM + lane];
            a1 += gk * enc_w2[k * DDIM + lane + 64];
        }
        table[r * DDIM + lane]      = a0;
        table[r * DDIM + lane + 64] = a1;
    }
}

// ------------------------------ K2 ----------------------------------------
__device__ __noinline__ void slow_path(
    unsigned int info, int q,
    const float* __restrict__ agg_w1, const float* __restrict__ agg_b1,
    const float* __restrict__ agg_w2, const float* __restrict__ agg_b2,
    const float* __restrict__ enc_w1, const float* __restrict__ enc_b1,
    const float* __restrict__ enc_w2, const float* __restrict__ enc_b2,
    float4* v)
{
    const unsigned int c0  = info & 0x7FFu;
    const unsigned int c1  = (info >> 11) & 0x7FFu;
    const unsigned int snz = (info >> 22) & 7u;
    float s0 = 0.0f, s1 = 0.0f;
    for (int dd = 0; dd < DDIM; ++dd) {
        const float w1d = agg_w1[snz * DDIM + dd];
        const float b1d = agg_b1[dd];
        const float h = fmaxf((float)c0 * w1d + b1d, 0.0f)
                      + fmaxf((float)c1 * w1d + b1d, 0.0f);
        s0 += h * agg_w2[dd * 2 + 0];
        s1 += h * agg_w2[dd * 2 + 1];
    }
    const float y0 = agg_b2[0] + 0.5f * s0;
    const float y1 = agg_b2[1] + 0.5f * s1;
    float o0 = 2.0f * enc_b2[q * 4 + 0];
    float o1 = 2.0f * enc_b2[q * 4 + 1];
    float o2 = 2.0f * enc_b2[q * 4 + 2];
    float o3 = 2.0f * enc_b2[q * 4 + 3];
    for (int k = 0; k < DDIM; ++k) {
        const float w1e = enc_w1[k], b1e = enc_b1[k];
        const float gk = fmaxf(y0 * w1e + b1e, 0.0f)
                       + fmaxf(y1 * w1e + b1e, 0.0f);
        o0 += gk * enc_w2[k * DDIM + q * 4 + 0];
        o1 += gk * enc_w2[k * DDIM + q * 4 + 1];
        o2 += gk * enc_w2[k * DDIM + q * 4 + 2];
        o3 += gk * enc_w2[k * DDIM + q * 4 + 3];
    }
    *v = make_float4(o0, o1, o2, o3);
}

__global__ __launch_bounds__(256) void gather_kernel(
    const unsigned int* __restrict__ rowinfo,
    const float* __restrict__ table,
    const float* __restrict__ agg_w1, const float* __restrict__ agg_b1,
    const float* __restrict__ agg_w2, const float* __restrict__ agg_b2,
    const float* __restrict__ enc_w1, const float* __restrict__ enc_b1,
    const float* __restrict__ enc_w2, const float* __restrict__ enc_b2,
    float* __restrict__ out)
{
    const float4* table4 = (const float4*)table;
    float4* out4 = (float4*)out;
    const int base = blockIdx.x * 1024 + threadIdx.x;   // 1024 quads per block

    #pragma unroll
    for (int k = 0; k < 4; ++k) {
        const int gt   = base + k * 256;
        const int unit = gt >> 5;
        const int q    = gt & 31;
        const unsigned int info = rowinfo[unit];
        float4 v;
        if (!(info & 0x80000000u)) {
            v = table4[(info << 5) + q];
        } else {
            slow_path(info, q, agg_w1, agg_b1, agg_w2, agg_b2,
                      enc_w1, enc_b1, enc_w2, enc_b2, &v);
        }
        __builtin_nontemporal_store(v.x, &out4[gt].x);
        __builtin_nontemporal_store(v.y, &out4[gt].y);
        __builtin_nontemporal_store(v.z, &out4[gt].z);
        __builtin_nontemporal_store(v.w, &out4[gt].w);
    }
}

extern "C" void kernel_launch(void* const* d_in, const int* in_sizes, int n_in,
                              void* d_out, int out_size, void* d_ws, size_t ws_size,
                              hipStream_t stream)
{
    const int* src_ids = (const int*)d_in[0];
    const int* dst_ids = (const int*)d_in[1];
    const int* src_sn  = (const int*)d_in[2];
    const int* dst_sn  = (const int*)d_in[3];
    const float* agg_w1 = (const float*)d_in[5];
    const float* agg_b1 = (const float*)d_in[6];
    const float* agg_w2 = (const float*)d_in[7];
    const float* agg_b2 = (const float*)d_in[8];
    const float* enc_w1 = (const float*)d_in[9];
    const float* enc_b1 = (const float*)d_in[10];
    const float* enc_w2 = (const float*)d_in[11];
    const float* enc_b2 = (const float*)d_in[12];
    float* out = (float*)d_out;

    // ws: rowinfo[131072] u32 (512 KB) | table[2048*128] f32 (1 MB)
    unsigned int* rowinfo = (unsigned int*)d_ws;
    float* table = (float*)(rowinfo + NUNITS);

    prep_kernel<<<NBATCH + 128, 1024, 0, stream>>>(
        src_ids, dst_ids, src_sn, dst_sn,
        agg_w1, agg_b1, agg_w2, agg_b2,
        enc_w1, enc_b1, enc_w2, enc_b2,
        rowinfo, table);

    gather_kernel<<<NQUADS / 1024, 256, 0, stream>>>(
        rowinfo, table,
        agg_w1, agg_b1, agg_w2, agg_b2,
        enc_w1, enc_b1, enc_w2, enc_b2, out);
}

// Round 5
// 114.598 us; speedup vs baseline: 2.8083x; 1.1043x over previous
//
#include <hip/hip_runtime.h>

// DTFormer: B=64, L=1024, S=8, D=128
// Three-kernel pipeline:
//  K1 prep (192 blocks x 1024):
//    blocks 0..63   : per-batch LDS histogram over packed (id,snap) keys ->
//                     per-unit CLAMPED table row index; slow units (count>=16,
//                     never on this input) appended to per-batch compact list
//    blocks 64..191 : Phi table [8][16][16][128], one row per wave,
//                     shuffle-reduce
//  K2 gather: branch-free, call-free: rowinfo -> table float4 -> single
//             nontemporal 16B store. 67 MB coalesced write (the roofline pass).
//  K3 fixup: 64 blocks; exactly recomputes + overwrites slow units (no-op here).

#define LSEQ    1024
#define NBATCH  64
#define DDIM    128
#define NKEYS   16384
#define CMAX    16
#define NUNITS  (2 * NBATCH * LSEQ)          // 131072
#define NQUADS  (NUNITS * (DDIM / 4))        // 4194304 float4s of output

typedef float f4 __attribute__((ext_vector_type(4)));

__device__ __forceinline__ unsigned int umin_u(unsigned int a, unsigned int b) {
    return a < b ? a : b;
}

// ------------------------------ K1 ----------------------------------------
__global__ __launch_bounds__(1024) void prep_kernel(
    const int* __restrict__ src_ids, const int* __restrict__ dst_ids,
    const int* __restrict__ src_sn,  const int* __restrict__ dst_sn,
    const float* __restrict__ agg_w1, const float* __restrict__ agg_b1,
    const float* __restrict__ agg_w2, const float* __restrict__ agg_b2,
    const float* __restrict__ enc_w1, const float* __restrict__ enc_b1,
    const float* __restrict__ enc_w2, const float* __restrict__ enc_b2,
    unsigned int* __restrict__ rowinfo, float* __restrict__ table,
    unsigned int* __restrict__ slowcnt, uint2* __restrict__ slowbuf)
{
    __shared__ unsigned int hist[NKEYS];   // src count lo16, dst count hi16
    __shared__ unsigned int slot;

    if (blockIdx.x < NBATCH) {
        // ---- per-batch histogram + rowinfo + slow list ----
        const int b = blockIdx.x;
        const int t = threadIdx.x;

        uint4* h4 = (uint4*)hist;
        const uint4 z = make_uint4(0u, 0u, 0u, 0u);
        #pragma unroll
        for (int i = 0; i < NKEYS / 4 / 1024; ++i) h4[t + i * 1024] = z;
        if (t == 0) slot = 0u;
        __syncthreads();

        const int base = b * LSEQ;
        const int sid = src_ids[base + t];
        const int ssn = src_sn[base + t];
        const int did = dst_ids[base + t];
        const int dsn = dst_sn[base + t];

        const unsigned int ssnz = (unsigned int)((ssn - 1) & 7);
        const unsigned int dsnz = (unsigned int)((dsn - 1) & 7);
        unsigned int skey = (unsigned int)(sid * 8) + ssnz;
        unsigned int dkey = (unsigned int)(did * 8) + dsnz;
        if (skey >= NKEYS) skey = NKEYS - 1;   // never hit: id < 2000
        if (dkey >= NKEYS) dkey = NKEYS - 1;

        atomicAdd(&hist[skey], 1u);
        atomicAdd(&hist[dkey], 65536u);
        __syncthreads();

        const unsigned int hs = hist[skey];
        const unsigned int hd = hist[dkey];
        const unsigned int sv = (sid != 0) ? 1u : 0u;
        const unsigned int dv = (did != 0) ? 1u : 0u;
        const unsigned int sc0 = (hs & 0xffffu) * sv;   // src self
        const unsigned int sc1 = (hs >> 16) * sv;       // src cross
        const unsigned int dc0 = (hd >> 16) * dv;       // dst self
        const unsigned int dc1 = (hd & 0xffffu) * dv;   // dst cross

        // clamped row index (always in-bounds); exact fixup handles >=16
        rowinfo[base + t] =
            (ssnz << 8) | (umin_u(sc0, CMAX - 1) << 4) | umin_u(sc1, CMAX - 1);
        rowinfo[NBATCH * LSEQ + base + t] =
            (dsnz << 8) | (umin_u(dc0, CMAX - 1) << 4) | umin_u(dc1, CMAX - 1);

        if (sc0 >= CMAX || sc1 >= CMAX) {
            const unsigned int e = atomicAdd(&slot, 1u);
            slowbuf[b * 2048 + e] =
                make_uint2((unsigned int)(base + t),
                           sc0 | (sc1 << 11) | (ssnz << 22));
        }
        if (dc0 >= CMAX || dc1 >= CMAX) {
            const unsigned int e = atomicAdd(&slot, 1u);
            slowbuf[b * 2048 + e] =
                make_uint2((unsigned int)(NBATCH * LSEQ + base + t),
                           dc0 | (dc1 << 11) | (dsnz << 22));
        }
        __syncthreads();
        if (t == 0) slowcnt[b] = slot;
    } else {
        // ---- Phi table: one row per wave, shuffle-reduce ----
        const int wave = threadIdx.x >> 6;
        const int lane = threadIdx.x & 63;
        const int r = (blockIdx.x - NBATCH) * 16 + wave;   // [0, 2048)
        const int sn = r >> 8;
        const int c0 = (r >> 4) & 15;
        const int c1 = r & 15;

        float p0 = 0.0f, p1 = 0.0f;
        #pragma unroll
        for (int half = 0; half < 2; ++half) {
            const int d = lane + half * 64;
            const float w1d = agg_w1[sn * DDIM + d];
            const float b1d = agg_b1[d];
            const float h = fmaxf((float)c0 * w1d + b1d, 0.0f)
                          + fmaxf((float)c1 * w1d + b1d, 0.0f);
            p0 += h * agg_w2[d * 2 + 0];
            p1 += h * agg_w2[d * 2 + 1];
        }
        #pragma unroll
        for (int m = 32; m; m >>= 1) {
            p0 += __shfl_xor(p0, m, 64);
            p1 += __shfl_xor(p1, m, 64);
        }
        const float y0 = agg_b2[0] + 0.5f * p0;
        const float y1 = agg_b2[1] + 0.5f * p1;

        float a0 = 2.0f * enc_b2[lane];
        float a1 = 2.0f * enc_b2[lane + 64];
        #pragma unroll 4
        for (int k = 0; k < DDIM; ++k) {
            const float w1e = enc_w1[k], b1e = enc_b1[k];
            const float gk = fmaxf(y0 * w1e + b1e, 0.0f)
                           + fmaxf(y1 * w1e + b1e, 0.0f);
            a0 += gk * enc_w2[k * DDIM + lane];
            a1 += gk * enc_w2[k * DDIM + lane + 64];
        }
        table[r * DDIM + lane]      = a0;
        table[r * DDIM + lane + 64] = a1;
    }
}

// ------------------------------ K2 ----------------------------------------
__global__ __launch_bounds__(256) void gather_kernel(
    const unsigned int* __restrict__ rowinfo,
    const float* __restrict__ table,
    float* __restrict__ out)
{
    const f4* table4 = (const f4*)table;
    f4* out4 = (f4*)out;
    const int base = blockIdx.x * 1024 + threadIdx.x;   // 1024 quads per block

    #pragma unroll
    for (int k = 0; k < 4; ++k) {
        const int gt = base + k * 256;
        const unsigned int info = rowinfo[gt >> 5];
        const f4 v = table4[(info << 5) + (gt & 31)];
        __builtin_nontemporal_store(v, &out4[gt]);
    }
}

// ------------------------------ K3 ----------------------------------------
__global__ __launch_bounds__(256) void fixup_kernel(
    const unsigned int* __restrict__ slowcnt,
    const uint2* __restrict__ slowbuf,
    const float* __restrict__ agg_w1, const float* __restrict__ agg_b1,
    const float* __restrict__ agg_w2, const float* __restrict__ agg_b2,
    const float* __restrict__ enc_w1, const float* __restrict__ enc_b1,
    const float* __restrict__ enc_w2, const float* __restrict__ enc_b2,
    float* __restrict__ out)
{
    const int b = blockIdx.x;
    const unsigned int n = slowcnt[b];
    if (n == 0u) return;                       // the always-taken path here

    const int q = threadIdx.x & 31;            // float4 index within D
    f4* out4 = (f4*)out;
    for (unsigned int e0 = 0; e0 < n; e0 += 8) {
        const unsigned int e = e0 + (threadIdx.x >> 5);
        if (e >= n) continue;
        const uint2 ent = slowbuf[b * 2048 + e];
        const unsigned int c0  = ent.y & 0x7FFu;
        const unsigned int c1  = (ent.y >> 11) & 0x7FFu;
        const unsigned int snz = (ent.y >> 22) & 7u;

        float s0 = 0.0f, s1 = 0.0f;
        for (int dd = 0; dd < DDIM; ++dd) {
            const float w1d = agg_w1[snz * DDIM + dd];
            const float b1d = agg_b1[dd];
            const float h = fmaxf((float)c0 * w1d + b1d, 0.0f)
                          + fmaxf((float)c1 * w1d + b1d, 0.0f);
            s0 += h * agg_w2[dd * 2 + 0];
            s1 += h * agg_w2[dd * 2 + 1];
        }
        const float y0 = agg_b2[0] + 0.5f * s0;
        const float y1 = agg_b2[1] + 0.5f * s1;
        f4 v;
        v.x = 2.0f * enc_b2[q * 4 + 0];
        v.y = 2.0f * enc_b2[q * 4 + 1];
        v.z = 2.0f * enc_b2[q * 4 + 2];
        v.w = 2.0f * enc_b2[q * 4 + 3];
        for (int k = 0; k < DDIM; ++k) {
            const float w1e = enc_w1[k], b1e = enc_b1[k];
            const float gk = fmaxf(y0 * w1e + b1e, 0.0f)
                           + fmaxf(y1 * w1e + b1e, 0.0f);
            v.x += gk * enc_w2[k * DDIM + q * 4 + 0];
            v.y += gk * enc_w2[k * DDIM + q * 4 + 1];
            v.z += gk * enc_w2[k * DDIM + q * 4 + 2];
            v.w += gk * enc_w2[k * DDIM + q * 4 + 3];
        }
        out4[ent.x * 32u + q] = v;
    }
}

extern "C" void kernel_launch(void* const* d_in, const int* in_sizes, int n_in,
                              void* d_out, int out_size, void* d_ws, size_t ws_size,
                              hipStream_t stream)
{
    const int* src_ids = (const int*)d_in[0];
    const int* dst_ids = (const int*)d_in[1];
    const int* src_sn  = (const int*)d_in[2];
    const int* dst_sn  = (const int*)d_in[3];
    const float* agg_w1 = (const float*)d_in[5];
    const float* agg_b1 = (const float*)d_in[6];
    const float* agg_w2 = (const float*)d_in[7];
    const float* agg_b2 = (const float*)d_in[8];
    const float* enc_w1 = (const float*)d_in[9];
    const float* enc_b1 = (const float*)d_in[10];
    const float* enc_w2 = (const float*)d_in[11];
    const float* enc_b2 = (const float*)d_in[12];
    float* out = (float*)d_out;

    // ws: rowinfo[131072] u32 | table[2048*128] f32 | slowcnt[64] u32 |
    //     pad to 8B | slowbuf[64*2048] uint2
    unsigned int* rowinfo = (unsigned int*)d_ws;
    float* table = (float*)(rowinfo + NUNITS);
    unsigned int* slowcnt = (unsigned int*)(table + 2048 * DDIM);
    uint2* slowbuf = (uint2*)(slowcnt + 64);

    prep_kernel<<<NBATCH + 128, 1024, 0, stream>>>(
        src_ids, dst_ids, src_sn, dst_sn,
        agg_w1, agg_b1, agg_w2, agg_b2,
        enc_w1, enc_b1, enc_w2, enc_b2,
        rowinfo, table, slowcnt, slowbuf);

    gather_kernel<<<NQUADS / 1024, 256, 0, stream>>>(rowinfo, table, out);

    fixup_kernel<<<NBATCH, 256, 0, stream>>>(
        slowcnt, slowbuf,
        agg_w1, agg_b1, agg_w2, agg_b2,
        enc_w1, enc_b1, enc_w2, enc_b2, out);
}